// Round 4
// baseline (26373.077 us; speedup 1.0000x reference)
//
#include <hip/hip_runtime.h>
#include <hip/hip_bf16.h>
#include <math.h>

#define BQ 64
#define TENC_ 512
#define TDEC_ 64
#define HH 1024
#define VV 1024
#define AA 512
#define NBLK 256

typedef short v8s __attribute__((ext_vector_type(8)));
typedef float v4f __attribute__((ext_vector_type(4)));
typedef unsigned short u16;

__device__ __forceinline__ u16 f2bf(float f) {
    unsigned u = __builtin_bit_cast(unsigned, f);
    u = u + 0x7FFFu + ((u >> 16) & 1u);
    return (u16)(u >> 16);
}
__device__ __forceinline__ float bf2f(u16 h) {
    unsigned u = ((unsigned)h) << 16;
    return __builtin_bit_cast(float, u);
}
__device__ __forceinline__ uint4 pack8(const float4 a, const float4 b) {
    uint4 o;
    o.x = (unsigned)f2bf(a.x) | ((unsigned)f2bf(a.y) << 16);
    o.y = (unsigned)f2bf(a.z) | ((unsigned)f2bf(a.w) << 16);
    o.z = (unsigned)f2bf(b.x) | ((unsigned)f2bf(b.y) << 16);
    o.w = (unsigned)f2bf(b.z) | ((unsigned)f2bf(b.w) << 16);
    return o;
}

// ---------------- conversion / layout kernels ----------------

__global__ void conv_f2b(const float* __restrict__ src, u16* __restrict__ dst, int n8) {
    int i = blockIdx.x * 256 + threadIdx.x;
    if (i >= n8) return;
    const float4 a = *(const float4*)(src + (size_t)i * 8);
    const float4 b = *(const float4*)(src + (size_t)i * 8 + 4);
    ((uint4*)dst)[i] = pack8(a, b);
}

__global__ void build_wcat(const float* __restrict__ wih, const float* __restrict__ whh,
                           u16* __restrict__ wcat) {
    int i = blockIdx.x * 256 + threadIdx.x;
    if (i >= 4096 * 2048 / 8) return;
    int row = i >> 8, k = (i & 255) * 8;
    const float* s = (k < 1024) ? (wih + (size_t)row * 1024 + k)
                                : (whh + (size_t)row * 1024 + (k - 1024));
    ((uint4*)wcat)[i] = pack8(*(const float4*)s, *(const float4*)(s + 4));
}

__global__ void embed_k(const int* __restrict__ tgt, const float* __restrict__ table,
                        u16* __restrict__ Eb) {
    int bid = blockIdx.x;            // t*64 + b
    int t = bid >> 6, b = bid & 63;
    int tok = (t == 0) ? 0 : tgt[b * TDEC_ + t - 1];
    int lane = threadIdx.x;
    const float* src = table + (size_t)tok * AA + lane * 8;
    ((uint4*)Eb)[(size_t)bid * 64 + lane] = pack8(*(const float4*)src, *(const float4*)(src + 4));
}

// ---------------- big MFMA GEMM: 128x128 tile ----------------
// OUT: 0=f32+bias, 1=bf16+bias, 2=f32+bias w/ (t*64+b)->(b*64+t) remap, 3=bf16+bias transposed Vt[b][n][t]
template<int OUT, bool AF32>
__global__ __launch_bounds__(256) void gemm_big(
    const void* __restrict__ Av, int lda,
    const u16* __restrict__ W, int ldw,
    const float* __restrict__ bias,
    void* __restrict__ outv, int ldo, int K) {
    __shared__ u16 As[128 * 128];
    __shared__ u16 Ws[128 * 128];
    const int tid = threadIdx.x;
    const int w = tid >> 6, lane = tid & 63;
    const int wm = w >> 1, wn = w & 1;
    const int li = lane & 15, lg = lane >> 4;
    const int mB = blockIdx.y * 128, nB = blockIdx.x * 128;
    v4f acc[4][4];
    #pragma unroll
    for (int mt = 0; mt < 4; ++mt)
        #pragma unroll
        for (int nt = 0; nt < 4; ++nt) acc[mt][nt] = (v4f){0.f, 0.f, 0.f, 0.f};
    for (int kc = 0; kc < K; kc += 128) {
        for (int it = 0; it < 8; ++it) {
            int flat = it * 256 + tid;
            int row = flat >> 4, c8 = flat & 15;
            uint4 val;
            if (AF32) {
                const float* Af = (const float*)Av + (size_t)(mB + row) * lda + kc + c8 * 8;
                val = pack8(*(const float4*)Af, *(const float4*)(Af + 4));
            } else {
                val = *(const uint4*)((const u16*)Av + (size_t)(mB + row) * lda + kc + c8 * 8);
            }
            int byte = (row * 256 + c8 * 16) ^ ((row & 7) << 4);
            *(uint4*)((char*)As + byte) = val;
            uint4 wv2 = *(const uint4*)(W + (size_t)(nB + row) * ldw + kc + c8 * 8);
            *(uint4*)((char*)Ws + byte) = wv2;
        }
        __syncthreads();
        for (int ks = 0; ks < 4; ++ks) {
            v8s wf[4];
            #pragma unroll
            for (int nt = 0; nt < 4; ++nt) {
                int row = wn * 64 + nt * 16 + li;
                int byte = (row * 256 + ks * 64 + lg * 16) ^ ((row & 7) << 4);
                wf[nt] = *(const v8s*)((char*)Ws + byte);
            }
            #pragma unroll
            for (int mt = 0; mt < 4; ++mt) {
                int row = wm * 64 + mt * 16 + li;
                int byte = (row * 256 + ks * 64 + lg * 16) ^ ((row & 7) << 4);
                v8s af = *(const v8s*)((char*)As + byte);
                #pragma unroll
                for (int nt = 0; nt < 4; ++nt)
                    acc[mt][nt] = __builtin_amdgcn_mfma_f32_16x16x32_bf16(af, wf[nt], acc[mt][nt], 0, 0, 0);
            }
        }
        __syncthreads();
    }
    #pragma unroll
    for (int mt = 0; mt < 4; ++mt) {
        #pragma unroll
        for (int r = 0; r < 4; ++r) {
            int m = mB + wm * 64 + mt * 16 + lg * 4 + r;
            #pragma unroll
            for (int nt = 0; nt < 4; ++nt) {
                int n = nB + wn * 64 + nt * 16 + li;
                float v = acc[mt][nt][r] + bias[n];
                if (OUT == 0) {
                    ((float*)outv)[(size_t)m * ldo + n] = v;
                } else if (OUT == 1) {
                    ((u16*)outv)[(size_t)m * ldo + n] = f2bf(v);
                } else if (OUT == 2) {
                    int mm = (m & 63) * TDEC_ + (m >> 6);
                    ((float*)outv)[(size_t)mm * ldo + n] = v;
                } else {
                    // Vt[b][n][t]: m = b*512 + t
                    ((u16*)outv)[(size_t)(m >> 9) * (AA * TENC_) + (size_t)n * TENC_ + (m & 511)] = f2bf(v);
                }
            }
        }
    }
}

// ---------------- persistent recurrence kernel ----------------

__device__ __forceinline__ void gbar(int* gcnt, int& idx) {
    __threadfence();
    __syncthreads();
    if (threadIdx.x == 0) {
        __hip_atomic_fetch_add(gcnt, 1, __ATOMIC_RELEASE, __HIP_MEMORY_SCOPE_AGENT);
        const int target = NBLK * (idx + 1);
        while (__hip_atomic_load(gcnt, __ATOMIC_ACQUIRE, __HIP_MEMORY_SCOPE_AGENT) < target)
            __builtin_amdgcn_s_sleep(2);
    }
    __syncthreads();
    __threadfence();
    idx++;
}

__device__ __forceinline__ void mbar(int* m, int target) {
    __threadfence();
    __syncthreads();
    if (threadIdx.x == 0) {
        __hip_atomic_fetch_add(m, 1, __ATOMIC_RELEASE, __HIP_MEMORY_SCOPE_AGENT);
        while (__hip_atomic_load(m, __ATOMIC_ACQUIRE, __HIP_MEMORY_SCOPE_AGENT) < target)
            __builtin_amdgcn_s_sleep(2);
    }
    __syncthreads();
    __threadfence();
}

// gates GEMM phase: M=64, N-tile 64 (nB), K-chunk 512 (kc). W row stride 2048.
__device__ __forceinline__ void gates_phase(const u16* __restrict__ A, int lda,
                                            const u16* __restrict__ W,
                                            u16* As, float* __restrict__ gp,
                                            int nB, int kc, int tid) {
    for (int it = 0; it < 16; ++it) {
        int flat = it * 256 + tid;
        int row = flat >> 6, c8 = flat & 63;
        uint4 v = *(const uint4*)(A + (size_t)row * lda + c8 * 8);
        int byte = (row * 1024 + c8 * 16) ^ ((row & 7) << 4);
        *(uint4*)((char*)As + byte) = v;
    }
    __syncthreads();
    const int w = tid >> 6, lane = tid & 63;
    const int li = lane & 15, lg = lane >> 4;
    const u16* Wp = W + (size_t)(nB * 64 + w * 16 + li) * 2048 + lg * 8;
    v4f acc[4];
    #pragma unroll
    for (int mt = 0; mt < 4; ++mt) acc[mt] = (v4f){0.f, 0.f, 0.f, 0.f};
    for (int ks = 0; ks < 16; ++ks) {
        v8s wf = *(const v8s*)(Wp + ks * 32);
        #pragma unroll
        for (int mt = 0; mt < 4; ++mt) {
            int row = mt * 16 + li;
            int byte = (row * 1024 + ks * 64 + lg * 16) ^ ((row & 7) << 4);
            v8s af = *(const v8s*)((char*)As + byte);
            acc[mt] = __builtin_amdgcn_mfma_f32_16x16x32_bf16(af, wf, acc[mt], 0, 0, 0);
        }
    }
    const int col = nB * 64 + w * 16 + li;
    float* g = gp + (size_t)kc * 64 * 4096;
    #pragma unroll
    for (int mt = 0; mt < 4; ++mt) {
        #pragma unroll
        for (int r = 0; r < 4; ++r) {
            int b = mt * 16 + lg * 4 + r;
            g[(size_t)b * 4096 + col] = acc[mt][r];
        }
    }
}

__device__ __forceinline__ void cell_phase(const float* __restrict__ gp,
                                           const float* __restrict__ bih, const float* __restrict__ bhh,
                                           float* __restrict__ c, u16* __restrict__ h,
                                           u16* __restrict__ hAll, int bid, int tid) {
    int idx = bid * 256 + tid;
    int hh = idx & 1023, b = idx >> 10;
    float g4[4];
    #pragma unroll
    for (int g = 0; g < 4; ++g) {
        int col = g * 1024 + hh;
        float s = bih[col] + bhh[col];
        #pragma unroll
        for (int kc = 0; kc < 4; ++kc) s += gp[((size_t)(kc * 64 + b)) * 4096 + col];
        g4[g] = s;
    }
    float ii = 1.f / (1.f + expf(-g4[0]));
    float ff = 1.f / (1.f + expf(-g4[1]));
    float oo = 1.f / (1.f + expf(-g4[3]));
    float c2 = ff * c[idx] + ii * tanhf(g4[2]);
    float hv = oo * tanhf(c2);
    c[idx] = c2;
    h[idx] = f2bf(hv);
    if (hAll) hAll[idx] = f2bf(hv);
}

__global__ __launch_bounds__(256) void recur_k(
    const u16* __restrict__ Eb, const u16* __restrict__ wcat0, const u16* __restrict__ wcat1,
    const u16* __restrict__ wqb, const u16* __restrict__ Kb, const u16* __restrict__ Vt,
    const float* __restrict__ bih0, const float* __restrict__ bhh0,
    const float* __restrict__ bih1, const float* __restrict__ bhh1,
    const float* __restrict__ bq,
    float* __restrict__ gp, float* __restrict__ qbuf, float* __restrict__ sraw,
    u16* __restrict__ h0b, u16* __restrict__ h1b, u16* __restrict__ attnb,
    float* __restrict__ c0, float* __restrict__ c1, u16* __restrict__ h1a,
    int* gcnt, int* mbc) {
    __shared__ __align__(16) char smem[65536];
    u16* As = (u16*)smem;
    const int tid = threadIdx.x;
    const int bid = blockIdx.x;
    int bar = 0;
    for (int t = 0; t < TDEC_; ++t) {
        // ---- L0: gates0 partials ----
        {
            const int nB = bid & 63, kc = bid >> 6;
            const u16* A; int lda;
            if (kc == 0)      { A = Eb + (size_t)t * BQ * AA; lda = AA; }
            else if (kc == 1) { A = attnb;      lda = AA; }
            else if (kc == 2) { A = h0b;        lda = HH; }
            else              { A = h0b + 512;  lda = HH; }
            gates_phase(A, lda, wcat0 + kc * 512, As, gp, nB, kc, tid);
        }
        gbar(gcnt, bar);
        // ---- C0 ----
        cell_phase(gp, bih0, bhh0, c0, h0b, nullptr, bid, tid);
        gbar(gcnt, bar);
        // ---- L1: gates1 partials ----
        {
            const int nB = bid & 63, kc = bid >> 6;
            const u16* A; int lda = HH;
            if (kc == 0)      A = h0b;
            else if (kc == 1) A = h0b + 512;
            else if (kc == 2) A = h1b;
            else              A = h1b + 512;
            gates_phase(A, lda, wcat1 + kc * 512, As, gp, nB, kc, tid);
        }
        gbar(gcnt, bar);
        // ---- C1 ----
        cell_phase(gp, bih1, bhh1, c1, h1b, h1a + (size_t)t * BQ * HH, bid, tid);
        gbar(gcnt, bar);
        // ---- QS: q -> scores -> softmax -> attn.V  (skip at last step) ----
        if (t < TDEC_ - 1) {
            const int b = bid >> 2, qd = bid & 3;
            float* qs  = (float*)smem;            // 512 f32
            u16*  h1s  = (u16*)(smem + 2048);     // 1024 bf16
            float* ps  = (float*)(smem + 4096);   // 512 f32
            float* red = (float*)(smem + 6144);   // 256 f32
            if (tid < 128) ((uint4*)h1s)[tid] = ((const uint4*)(h1b + (size_t)b * HH))[tid];
            __syncthreads();
            // q slice: a in [qd*128, qd*128+128), each pair of threads splits K=1024
            {
                int a = qd * 128 + (tid >> 1), half = tid & 1;
                const u16* wr = wqb + (size_t)a * HH + half * 512;
                const u16* hr = h1s + half * 512;
                float s = 0.f;
                #pragma unroll 8
                for (int k8 = 0; k8 < 64; ++k8) {
                    v8s wv = *(const v8s*)(wr + k8 * 8);
                    #pragma unroll
                    for (int e = 0; e < 8; ++e)
                        s = fmaf(bf2f((u16)wv[e]), bf2f(hr[k8 * 8 + e]), s);
                }
                s += __shfl_xor(s, 1);
                if (half == 0) qbuf[(size_t)b * AA + a] = s + bq[a];
            }
            mbar(&mbc[b], 8 * t + 4);
            qs[tid] = qbuf[(size_t)b * AA + tid];
            qs[tid + 256] = qbuf[(size_t)b * AA + tid + 256];
            __syncthreads();
            // scores: t-rows [qd*128, qd*128+128), one wave does 32 rows
            {
                int w = tid >> 6, lane = tid & 63;
                float qf[8];
                #pragma unroll
                for (int e = 0; e < 8; ++e) qf[e] = qs[lane * 8 + e];
                for (int r = 0; r < 32; ++r) {
                    int tt = qd * 128 + w * 32 + r;
                    v8s kv = *(const v8s*)(Kb + ((size_t)b * TENC_ + tt) * AA + lane * 8);
                    float s = 0.f;
                    #pragma unroll
                    for (int e = 0; e < 8; ++e) s = fmaf(bf2f((u16)kv[e]), qf[e], s);
                    s += __shfl_xor(s, 1);  s += __shfl_xor(s, 2);
                    s += __shfl_xor(s, 4);  s += __shfl_xor(s, 8);
                    s += __shfl_xor(s, 16); s += __shfl_xor(s, 32);
                    if (lane == 0) sraw[(size_t)b * TENC_ + tt] = s;
                }
            }
            mbar(&mbc[b], 8 * t + 8);
            // softmax over 512 (redundant in each sibling block)
            {
                float v0 = sraw[(size_t)b * TENC_ + tid], v1 = sraw[(size_t)b * TENC_ + 256 + tid];
                red[tid] = fmaxf(v0, v1);
                __syncthreads();
                for (int off = 128; off; off >>= 1) {
                    if (tid < off) red[tid] = fmaxf(red[tid], red[tid + off]);
                    __syncthreads();
                }
                float m = red[0];
                __syncthreads();
                float e0 = expf(v0 - m), e1 = expf(v1 - m);
                red[tid] = e0 + e1;
                __syncthreads();
                for (int off = 128; off; off >>= 1) {
                    if (tid < off) red[tid] += red[tid + off];
                    __syncthreads();
                }
                float inv = 1.f / red[0];
                ps[tid] = e0 * inv; ps[tid + 256] = e1 * inv;
                __syncthreads();
            }
            // attnout: a in [qd*128, qd*128+128), pair of threads splits t=512
            {
                int a = qd * 128 + (tid >> 1), th = tid & 1;
                const u16* vr = Vt + ((size_t)b * AA + a) * TENC_ + th * 256;
                float s = 0.f;
                #pragma unroll 8
                for (int t8 = 0; t8 < 32; ++t8) {
                    v8s vv = *(const v8s*)(vr + t8 * 8);
                    #pragma unroll
                    for (int e = 0; e < 8; ++e)
                        s = fmaf(bf2f((u16)vv[e]), ps[th * 256 + t8 * 8 + e], s);
                }
                s += __shfl_xor(s, 1);
                if (th == 0) attnb[(size_t)b * AA + a] = f2bf(s);
            }
            gbar(gcnt, bar);
        }
    }
}

// ---------------- LayerNorm+ReLU, bf16 in-place ----------------
__global__ __launch_bounds__(256) void ln_relu_b(u16* __restrict__ x, const float* __restrict__ g,
                                                 const float* __restrict__ bb) {
    int row = blockIdx.x, tid = threadIdx.x;
    u16* xr = x + (size_t)row * 2048;
    __shared__ float red[256];
    uint4 v = *(const uint4*)(xr + tid * 8);
    const u16* pv = (const u16*)&v;
    float lv[8];
    float s = 0.f;
    #pragma unroll
    for (int e = 0; e < 8; ++e) { lv[e] = bf2f(pv[e]); s += lv[e]; }
    red[tid] = s;
    __syncthreads();
    for (int off = 128; off; off >>= 1) {
        if (tid < off) red[tid] += red[tid + off];
        __syncthreads();
    }
    float mu = red[0] * (1.f / 2048.f);
    __syncthreads();
    s = 0.f;
    #pragma unroll
    for (int e = 0; e < 8; ++e) { float d = lv[e] - mu; s += d * d; }
    red[tid] = s;
    __syncthreads();
    for (int off = 128; off; off >>= 1) {
        if (tid < off) red[tid] += red[tid + off];
        __syncthreads();
    }
    float inv = rsqrtf(red[0] * (1.f / 2048.f) + 1e-5f);
    const float4 g1 = *(const float4*)(g + tid * 8), g2 = *(const float4*)(g + tid * 8 + 4);
    const float4 b1 = *(const float4*)(bb + tid * 8), b2 = *(const float4*)(bb + tid * 8 + 4);
    float gv[8] = {g1.x, g1.y, g1.z, g1.w, g2.x, g2.y, g2.z, g2.w};
    float bv[8] = {b1.x, b1.y, b1.z, b1.w, b2.x, b2.y, b2.z, b2.w};
    float o[8];
    #pragma unroll
    for (int e = 0; e < 8; ++e) o[e] = fmaxf((lv[e] - mu) * inv * gv[e] + bv[e], 0.f);
    *(uint4*)(xr + tid * 8) = pack8(make_float4(o[0], o[1], o[2], o[3]),
                                    make_float4(o[4], o[5], o[6], o[7]));
}

// ---------------- loss ----------------
__global__ void ce_loss(const float* __restrict__ logits, const int* __restrict__ target,
                        float* __restrict__ acc) {
    const int r = blockIdx.x;
    const float* row = logits + (size_t)r * VV;
    const int tid = threadIdx.x;
    __shared__ float red[256];
    float lv[4];
    float m = -1e30f;
    #pragma unroll
    for (int i = 0; i < 4; ++i) { lv[i] = row[tid + i * 256]; m = fmaxf(m, lv[i]); }
    red[tid] = m;
    __syncthreads();
    for (int off = 128; off; off >>= 1) {
        if (tid < off) red[tid] = fmaxf(red[tid], red[tid + off]);
        __syncthreads();
    }
    m = red[0];
    __syncthreads();
    float s = 0.f;
    #pragma unroll
    for (int i = 0; i < 4; ++i) s += expf(lv[i] - m);
    red[tid] = s;
    __syncthreads();
    for (int off = 128; off; off >>= 1) {
        if (tid < off) red[tid] += red[tid + off];
        __syncthreads();
    }
    if (tid == 0) {
        const float nll = logf(red[0]) + m - row[target[r]];
        atomicAdd(acc, nll);
    }
}

__global__ void finalize_loss(const float* __restrict__ acc, float* __restrict__ out) {
    out[0] = acc[0] * (1.f / 4096.f);
}

// ---------------- host ----------------
extern "C" void kernel_launch(void* const* d_in, const int* in_sizes, int n_in,
                              void* d_out, int out_size, void* d_ws, size_t ws_size,
                              hipStream_t stream) {
    const float* enc       = (const float*)d_in[0];
    const int*   target    = (const int*)d_in[1];
    const float* emb_table = (const float*)d_in[2];
    const float* att_wq    = (const float*)d_in[3];
    const float* att_bq    = (const float*)d_in[4];
    const float* att_wk    = (const float*)d_in[5];
    const float* att_bk    = (const float*)d_in[6];
    const float* att_wv    = (const float*)d_in[7];
    const float* att_bv    = (const float*)d_in[8];
    const float* w_ih0     = (const float*)d_in[9];
    const float* w_hh0     = (const float*)d_in[10];
    const float* b_ih0     = (const float*)d_in[11];
    const float* b_hh0     = (const float*)d_in[12];
    const float* w_ih1     = (const float*)d_in[13];
    const float* w_hh1     = (const float*)d_in[14];
    const float* b_ih1     = (const float*)d_in[15];
    const float* b_hh1     = (const float*)d_in[16];
    const float* mlp_w1    = (const float*)d_in[17];
    const float* mlp_b1    = (const float*)d_in[18];
    const float* ln_g      = (const float*)d_in[19];
    const float* ln_b      = (const float*)d_in[20];
    const float* mlp_w2    = (const float*)d_in[21];
    const float* mlp_b2    = (const float*)d_in[22];
    float* out = (float*)d_out;
    char* ws = (char*)d_ws;

    size_t off = 0;
    auto alloc = [&](size_t bytes) { size_t o = off; off += (bytes + 255) & ~(size_t)255; return o; };
    u16*   Kb    = (u16*)(ws + alloc((size_t)BQ * TENC_ * AA * 2));
    u16*   Vt    = (u16*)(ws + alloc((size_t)BQ * TENC_ * AA * 2));   // [b][a][t]
    u16*   Eb    = (u16*)(ws + alloc((size_t)TDEC_ * BQ * AA * 2));
    u16*   wcat0 = (u16*)(ws + alloc((size_t)4096 * 2048 * 2));
    u16*   wcat1 = (u16*)(ws + alloc((size_t)4096 * 2048 * 2));
    u16*   wkb   = (u16*)(ws + alloc((size_t)AA * HH * 2));
    u16*   wvb   = (u16*)(ws + alloc((size_t)AA * HH * 2));
    u16*   wqb   = (u16*)(ws + alloc((size_t)AA * HH * 2));
    u16*   w1b   = (u16*)(ws + alloc((size_t)2 * VV * HH * 2));
    u16*   w2b   = (u16*)(ws + alloc((size_t)VV * 2 * VV * 2));
    float* gp    = (float*)(ws + alloc((size_t)4 * 64 * 4096 * 4));
    float* qbuf  = (float*)(ws + alloc((size_t)BQ * AA * 4));
    float* sraw  = (float*)(ws + alloc((size_t)BQ * TENC_ * 4));
    u16*   h0b   = (u16*)(ws + alloc((size_t)BQ * HH * 2));
    u16*   h1b   = (u16*)(ws + alloc((size_t)BQ * HH * 2));
    u16*   attnb = (u16*)(ws + alloc((size_t)BQ * AA * 2));
    float* c0    = (float*)(ws + alloc((size_t)BQ * HH * 4));
    float* c1    = (float*)(ws + alloc((size_t)BQ * HH * 4));
    u16*   h1a   = (u16*)(ws + alloc((size_t)TDEC_ * BQ * HH * 2));
    u16*   x1b   = (u16*)(ws + alloc((size_t)TDEC_ * BQ * 2 * VV * 2));
    float* lacc  = (float*)(ws + alloc(256));
    int*   barr  = (int*)(ws + alloc(4096));      // [0]=gcnt, [64..127]=mbc
    int* gcnt = barr;
    int* mbc  = barr + 64;

    // ---- prologue ----
    build_wcat<<<4096, 256, 0, stream>>>(w_ih0, w_hh0, wcat0);
    build_wcat<<<4096, 256, 0, stream>>>(w_ih1, w_hh1, wcat1);
    conv_f2b<<<256, 256, 0, stream>>>(att_wk, wkb, AA * HH / 8);
    conv_f2b<<<256, 256, 0, stream>>>(att_wv, wvb, AA * HH / 8);
    conv_f2b<<<256, 256, 0, stream>>>(att_wq, wqb, AA * HH / 8);
    conv_f2b<<<1024, 256, 0, stream>>>(mlp_w1, w1b, 2 * VV * HH / 8);
    conv_f2b<<<1024, 256, 0, stream>>>(mlp_w2, w2b, VV * 2 * VV / 8);
    embed_k<<<TDEC_ * BQ, 64, 0, stream>>>(target, emb_table, Eb);

    hipMemsetAsync(h0b, 0, (size_t)BQ * HH * 2, stream);
    hipMemsetAsync(h1b, 0, (size_t)BQ * HH * 2, stream);
    hipMemsetAsync(attnb, 0, (size_t)BQ * AA * 2, stream);
    hipMemsetAsync(c0, 0, (size_t)BQ * HH * 4, stream);
    hipMemsetAsync(c1, 0, (size_t)BQ * HH * 4, stream);
    hipMemsetAsync(lacc, 0, 4, stream);
    hipMemsetAsync(barr, 0, 4096, stream);

    gemm_big<1, true><<<dim3(4, 256), 256, 0, stream>>>(enc, HH, wkb, HH, att_bk, Kb, AA, HH);
    gemm_big<3, true><<<dim3(4, 256), 256, 0, stream>>>(enc, HH, wvb, HH, att_bv, Vt, 0, HH);

    // ---- recurrence: one persistent kernel, 256 co-resident blocks ----
    recur_k<<<NBLK, 256, 0, stream>>>(Eb, wcat0, wcat1, wqb, Kb, Vt,
                                      b_ih0, b_hh0, b_ih1, b_hh1, att_bq,
                                      gp, qbuf, sraw, h0b, h1b, attnb, c0, c1, h1a,
                                      gcnt, mbc);

    // ---- batched MLP head ----
    gemm_big<1, false><<<dim3(16, 32), 256, 0, stream>>>(h1a, HH, w1b, HH, mlp_b1, x1b, 2 * VV, HH);
    ln_relu_b<<<TDEC_ * BQ, 256, 0, stream>>>(x1b, ln_g, ln_b);
    gemm_big<2, false><<<dim3(8, 32), 256, 0, stream>>>(x1b, 2 * VV, w2b, 2 * VV, mlp_b2, out, VV, 2 * VV);

    ce_loss<<<BQ * TDEC_, 256, 0, stream>>>(out, target, lacc);
    finalize_loss<<<1, 1, 0, stream>>>(lacc, out + (size_t)BQ * TDEC_ * VV);
}

// Round 5
// 18221.036 us; speedup vs baseline: 1.4474x; 1.4474x over previous
//
#include <hip/hip_runtime.h>
#include <hip/hip_bf16.h>
#include <math.h>

#define BQ 64
#define TENC_ 512
#define TDEC_ 64
#define HH 1024
#define VV 1024
#define AA 512
#define NBLK 128

typedef short v8s __attribute__((ext_vector_type(8)));
typedef float v4f __attribute__((ext_vector_type(4)));
typedef unsigned short u16;

__device__ __forceinline__ u16 f2bf(float f) {
    unsigned u = __builtin_bit_cast(unsigned, f);
    u = u + 0x7FFFu + ((u >> 16) & 1u);
    return (u16)(u >> 16);
}
__device__ __forceinline__ float bf2f(u16 h) {
    unsigned u = ((unsigned)h) << 16;
    return __builtin_bit_cast(float, u);
}
__device__ __forceinline__ uint4 pack8(const float4 a, const float4 b) {
    uint4 o;
    o.x = (unsigned)f2bf(a.x) | ((unsigned)f2bf(a.y) << 16);
    o.y = (unsigned)f2bf(a.z) | ((unsigned)f2bf(a.w) << 16);
    o.z = (unsigned)f2bf(b.x) | ((unsigned)f2bf(b.y) << 16);
    o.w = (unsigned)f2bf(b.z) | ((unsigned)f2bf(b.w) << 16);
    return o;
}

// ---------------- conversion / layout kernels ----------------

__global__ void conv_f2b(const float* __restrict__ src, u16* __restrict__ dst, int n8) {
    int i = blockIdx.x * 256 + threadIdx.x;
    if (i >= n8) return;
    const float4 a = *(const float4*)(src + (size_t)i * 8);
    const float4 b = *(const float4*)(src + (size_t)i * 8 + 4);
    ((uint4*)dst)[i] = pack8(a, b);
}

// wpack[(j*32 + r)][k], r = gate*8 + uu, orig row = gate*1024 + j*8 + uu; k<1024: wih, else whh.
// bpk[j*32+r] = bih[orig] + bhh[orig]
__global__ void build_wpack(const float* __restrict__ wih, const float* __restrict__ whh,
                            const float* __restrict__ bih, const float* __restrict__ bhh,
                            u16* __restrict__ wpack, float* __restrict__ bpk) {
    int i = blockIdx.x * 256 + threadIdx.x;
    if (i >= 4096 * 2048 / 8) return;
    int rowp = i >> 8, k = (i & 255) * 8;
    int j = rowp >> 5, r = rowp & 31;
    int orig = ((r >> 3) << 10) + j * 8 + (r & 7);
    const float* s = (k < 1024) ? (wih + (size_t)orig * 1024 + k)
                                : (whh + (size_t)orig * 1024 + (k - 1024));
    ((uint4*)wpack)[i] = pack8(*(const float4*)s, *(const float4*)(s + 4));
    if (k == 0) bpk[rowp] = bih[orig] + bhh[orig];
}

__global__ void embed_k(const int* __restrict__ tgt, const float* __restrict__ table,
                        u16* __restrict__ Eb) {
    int bid = blockIdx.x;            // t*64 + b
    int t = bid >> 6, b = bid & 63;
    int tok = (t == 0) ? 0 : tgt[b * TDEC_ + t - 1];
    int lane = threadIdx.x;
    const float* src = table + (size_t)tok * AA + lane * 8;
    ((uint4*)Eb)[(size_t)bid * 64 + lane] = pack8(*(const float4*)src, *(const float4*)(src + 4));
}

// ---------------- big MFMA GEMM: 128x128 tile ----------------
// OUT: 0=f32+bias, 1=bf16+bias, 2=f32+bias w/ (t*64+b)->(b*64+t) remap, 3=bf16+bias transposed Vt[b][n][t]
template<int OUT, bool AF32>
__global__ __launch_bounds__(256) void gemm_big(
    const void* __restrict__ Av, int lda,
    const u16* __restrict__ W, int ldw,
    const float* __restrict__ bias,
    void* __restrict__ outv, int ldo, int K) {
    __shared__ u16 As[128 * 128];
    __shared__ u16 Ws[128 * 128];
    const int tid = threadIdx.x;
    const int w = tid >> 6, lane = tid & 63;
    const int wm = w >> 1, wn = w & 1;
    const int li = lane & 15, lg = lane >> 4;
    const int mB = blockIdx.y * 128, nB = blockIdx.x * 128;
    v4f acc[4][4];
    #pragma unroll
    for (int mt = 0; mt < 4; ++mt)
        #pragma unroll
        for (int nt = 0; nt < 4; ++nt) acc[mt][nt] = (v4f){0.f, 0.f, 0.f, 0.f};
    for (int kc = 0; kc < K; kc += 128) {
        for (int it = 0; it < 8; ++it) {
            int flat = it * 256 + tid;
            int row = flat >> 4, c8 = flat & 15;
            uint4 val;
            if (AF32) {
                const float* Af = (const float*)Av + (size_t)(mB + row) * lda + kc + c8 * 8;
                val = pack8(*(const float4*)Af, *(const float4*)(Af + 4));
            } else {
                val = *(const uint4*)((const u16*)Av + (size_t)(mB + row) * lda + kc + c8 * 8);
            }
            int byte = (row * 256 + c8 * 16) ^ ((row & 7) << 4);
            *(uint4*)((char*)As + byte) = val;
            uint4 wv2 = *(const uint4*)(W + (size_t)(nB + row) * ldw + kc + c8 * 8);
            *(uint4*)((char*)Ws + byte) = wv2;
        }
        __syncthreads();
        for (int ks = 0; ks < 4; ++ks) {
            v8s wf[4];
            #pragma unroll
            for (int nt = 0; nt < 4; ++nt) {
                int row = wn * 64 + nt * 16 + li;
                int byte = (row * 256 + ks * 64 + lg * 16) ^ ((row & 7) << 4);
                wf[nt] = *(const v8s*)((char*)Ws + byte);
            }
            #pragma unroll
            for (int mt = 0; mt < 4; ++mt) {
                int row = wm * 64 + mt * 16 + li;
                int byte = (row * 256 + ks * 64 + lg * 16) ^ ((row & 7) << 4);
                v8s af = *(const v8s*)((char*)As + byte);
                #pragma unroll
                for (int nt = 0; nt < 4; ++nt)
                    acc[mt][nt] = __builtin_amdgcn_mfma_f32_16x16x32_bf16(af, wf[nt], acc[mt][nt], 0, 0, 0);
            }
        }
        __syncthreads();
    }
    #pragma unroll
    for (int mt = 0; mt < 4; ++mt) {
        #pragma unroll
        for (int r = 0; r < 4; ++r) {
            int m = mB + wm * 64 + mt * 16 + lg * 4 + r;
            #pragma unroll
            for (int nt = 0; nt < 4; ++nt) {
                int n = nB + wn * 64 + nt * 16 + li;
                float v = acc[mt][nt][r] + bias[n];
                if (OUT == 0) {
                    ((float*)outv)[(size_t)m * ldo + n] = v;
                } else if (OUT == 1) {
                    ((u16*)outv)[(size_t)m * ldo + n] = f2bf(v);
                } else if (OUT == 2) {
                    int mm = (m & 63) * TDEC_ + (m >> 6);
                    ((float*)outv)[(size_t)mm * ldo + n] = v;
                } else {
                    ((u16*)outv)[(size_t)(m >> 9) * (AA * TENC_) + (size_t)n * TENC_ + (m & 511)] = f2bf(v);
                }
            }
        }
    }
}

// ---------------- persistent recurrence kernel ----------------

// flag-array barrier: 1 release store per block, block0 polls all, broadcasts epoch
__device__ __forceinline__ void gbar(int* flags, int* epoch, int bid, int& n) {
    ++n;
    __threadfence();
    __syncthreads();
    if (bid == 0) {
        if (threadIdx.x == 0)
            __hip_atomic_store(&flags[0], n, __ATOMIC_RELEASE, __HIP_MEMORY_SCOPE_AGENT);
        if (threadIdx.x < NBLK)
            while (__hip_atomic_load(&flags[threadIdx.x], __ATOMIC_ACQUIRE, __HIP_MEMORY_SCOPE_AGENT) < n)
                __builtin_amdgcn_s_sleep(2);
        __syncthreads();
        if (threadIdx.x == 0)
            __hip_atomic_store(epoch, n, __ATOMIC_RELEASE, __HIP_MEMORY_SCOPE_AGENT);
    } else {
        if (threadIdx.x == 0) {
            __hip_atomic_store(&flags[bid], n, __ATOMIC_RELEASE, __HIP_MEMORY_SCOPE_AGENT);
            while (__hip_atomic_load(epoch, __ATOMIC_ACQUIRE, __HIP_MEMORY_SCOPE_AGENT) < n)
                __builtin_amdgcn_s_sleep(2);
        }
    }
    __syncthreads();
    __threadfence();
}

// 2-block pair barrier (siblings of one batch)
__device__ __forceinline__ void mbar(int* m, int target) {
    __threadfence();
    __syncthreads();
    if (threadIdx.x == 0) {
        __hip_atomic_fetch_add(m, 1, __ATOMIC_ACQ_REL, __HIP_MEMORY_SCOPE_AGENT);
        while (__hip_atomic_load(m, __ATOMIC_ACQUIRE, __HIP_MEMORY_SCOPE_AGENT) < target)
            __builtin_amdgcn_s_sleep(2);
    }
    __syncthreads();
    __threadfence();
}

// fused gates(full-K, unit-sliced) + LSTM cell. Block bid owns units [bid*8, bid*8+8),
// i.e. packed weight rows [bid*32, bid*32+32). M=64 batches, N=32 cols, K=2048.
__device__ __forceinline__ void lstm_phase(
    int phase, int bid, int tid,
    const u16* __restrict__ s0, const u16* __restrict__ s1, const u16* __restrict__ s2,
    const u16* __restrict__ h0c, const u16* __restrict__ h1p,
    const u16* __restrict__ wpack, const float* __restrict__ bpk,
    float* __restrict__ cst, u16* __restrict__ hout, u16* __restrict__ h1a_t,
    char* smem)
{
    const int lane = tid & 63, li = lane & 15, lg = lane >> 4, w = tid >> 6;

    auto srcp = [&](int c, int row, int k2) -> const u16* {
        int k = c * 256 + k2;
        if (phase == 0) {
            if (k < 512)  return s0 + row * 512 + k;
            if (k < 1024) return s1 + row * 512 + (k - 512);
            return s2 + row * 1024 + (k - 1024);
        } else {
            if (k < 1024) return h0c + row * 1024 + k;
            return h1p + row * 1024 + (k - 1024);
        }
    };
    uint4 rg[8];
    auto loadc = [&](int c) {
        #pragma unroll
        for (int it = 0; it < 8; ++it) {
            int flat = it * 256 + tid, row = flat >> 5, c16 = flat & 31;
            rg[it] = *(const uint4*)srcp(c, row, c16 * 8);
        }
    };
    auto writec = [&](int c) {
        char* buf = smem + (c & 1) * 32768;
        #pragma unroll
        for (int it = 0; it < 8; ++it) {
            int flat = it * 256 + tid, row = flat >> 5, c16 = flat & 31;
            int byte = (row * 512 + c16 * 16) ^ ((row & 7) << 4);
            *(uint4*)(buf + byte) = rg[it];
        }
    };

    loadc(0); writec(0); __syncthreads();
    v4f acc[2];
    acc[0] = (v4f){0.f, 0.f, 0.f, 0.f};
    acc[1] = (v4f){0.f, 0.f, 0.f, 0.f};
    const u16* wp0 = wpack + (size_t)(bid * 32 + li) * 2048;
    const u16* wp1 = wpack + (size_t)(bid * 32 + 16 + li) * 2048;
    for (int c = 0; c < 8; ++c) {
        if (c < 7) loadc(c + 1);
        char* buf = smem + (c & 1) * 32768;
        const int arow = w * 16 + li;
        #pragma unroll
        for (int ks = 0; ks < 8; ++ks) {
            v8s wf0 = *(const v8s*)(wp0 + c * 256 + ks * 32 + lg * 8);
            v8s wf1 = *(const v8s*)(wp1 + c * 256 + ks * 32 + lg * 8);
            int byte = (arow * 512 + ks * 64 + lg * 16) ^ ((arow & 7) << 4);
            v8s af = *(const v8s*)(buf + byte);
            acc[0] = __builtin_amdgcn_mfma_f32_16x16x32_bf16(af, wf0, acc[0], 0, 0, 0);
            acc[1] = __builtin_amdgcn_mfma_f32_16x16x32_bf16(af, wf1, acc[1], 0, 0, 0);
        }
        if (c < 7) writec(c + 1);
        __syncthreads();
    }
    // gates -> LDS [64][33] f32, then cell
    float* gl = (float*)smem;
    #pragma unroll
    for (int nt = 0; nt < 2; ++nt)
        #pragma unroll
        for (int r = 0; r < 4; ++r)
            gl[(w * 16 + lg * 4 + r) * 33 + nt * 16 + li] = acc[nt][r];
    __syncthreads();
    #pragma unroll
    for (int h = 0; h < 2; ++h) {
        int item = h * 256 + tid, m = item & 63, uu = item >> 6;
        float gi = gl[m * 33 + uu]      + bpk[bid * 32 + uu];
        float gf = gl[m * 33 + 8 + uu]  + bpk[bid * 32 + 8 + uu];
        float gg = gl[m * 33 + 16 + uu] + bpk[bid * 32 + 16 + uu];
        float go = gl[m * 33 + 24 + uu] + bpk[bid * 32 + 24 + uu];
        int ci = m * 1024 + bid * 8 + uu;
        float ii = 1.f / (1.f + expf(-gi));
        float ff = 1.f / (1.f + expf(-gf));
        float oo = 1.f / (1.f + expf(-go));
        float c2 = ff * cst[ci] + ii * tanhf(gg);
        float hv = oo * tanhf(c2);
        cst[ci] = c2;
        hout[ci] = f2bf(hv);
        if (h1a_t) h1a_t[ci] = f2bf(hv);
    }
    __syncthreads();
}

// fused q -> scores -> softmax -> attn.V : 2 sibling blocks per batch
__device__ __forceinline__ void attn_phase(
    int bid, int tid, int t,
    const u16* __restrict__ h1cur, const u16* __restrict__ wqb,
    const u16* __restrict__ Kb, const u16* __restrict__ Vt,
    const float* __restrict__ bq,
    float* __restrict__ qbuf, float* __restrict__ sraw, u16* __restrict__ attnb,
    int* __restrict__ mbc, char* smem)
{
    const int b = bid >> 1, qd = bid & 1;
    float* qs  = (float*)smem;             // 512 f32
    float* ps  = (float*)(smem + 2048);    // 512 f32
    float* red = (float*)(smem + 4096);    // 256 f32
    u16*   h1s = (u16*)(smem + 5120);      // 1024 bf16
    if (tid < 128) ((uint4*)h1s)[tid] = ((const uint4*)(h1cur + (size_t)b * HH))[tid];
    __syncthreads();
    // q: a = qd*256 + tid, full K=1024
    {
        int a = qd * 256 + tid;
        const u16* wr = wqb + (size_t)a * HH;
        float s = 0.f;
        #pragma unroll 8
        for (int k8 = 0; k8 < 128; ++k8) {
            v8s wv = *(const v8s*)(wr + k8 * 8);
            #pragma unroll
            for (int e = 0; e < 8; ++e)
                s = fmaf(bf2f((u16)wv[e]), bf2f(h1s[k8 * 8 + e]), s);
        }
        qbuf[(size_t)b * AA + a] = s + bq[a];
    }
    mbar(&mbc[b * 32], 4 * t + 2);
    qs[tid] = qbuf[(size_t)b * AA + tid];
    qs[tid + 256] = qbuf[(size_t)b * AA + 256 + tid];
    __syncthreads();
    // scores: rows tt in [qd*256, qd*256+256), one wave does 64 rows
    {
        int w = tid >> 6, lane = tid & 63;
        float qf[8];
        #pragma unroll
        for (int e = 0; e < 8; ++e) qf[e] = qs[lane * 8 + e];
        #pragma unroll 4
        for (int r = 0; r < 64; ++r) {
            int tt = qd * 256 + w * 64 + r;
            v8s kv = *(const v8s*)(Kb + ((size_t)b * TENC_ + tt) * AA + lane * 8);
            float s = 0.f;
            #pragma unroll
            for (int e = 0; e < 8; ++e) s = fmaf(bf2f((u16)kv[e]), qf[e], s);
            s += __shfl_xor(s, 1);  s += __shfl_xor(s, 2);
            s += __shfl_xor(s, 4);  s += __shfl_xor(s, 8);
            s += __shfl_xor(s, 16); s += __shfl_xor(s, 32);
            if (lane == 0) sraw[(size_t)b * TENC_ + tt] = s;
        }
    }
    mbar(&mbc[b * 32], 4 * t + 4);
    // softmax over 512 (redundant in both siblings)
    {
        float v0 = sraw[(size_t)b * TENC_ + tid], v1 = sraw[(size_t)b * TENC_ + 256 + tid];
        red[tid] = fmaxf(v0, v1);
        __syncthreads();
        for (int off = 128; off; off >>= 1) {
            if (tid < off) red[tid] = fmaxf(red[tid], red[tid + off]);
            __syncthreads();
        }
        float m = red[0];
        __syncthreads();
        float e0 = expf(v0 - m), e1 = expf(v1 - m);
        red[tid] = e0 + e1;
        __syncthreads();
        for (int off = 128; off; off >>= 1) {
            if (tid < off) red[tid] += red[tid + off];
            __syncthreads();
        }
        float inv = 1.f / red[0];
        ps[tid] = e0 * inv; ps[tid + 256] = e1 * inv;
        __syncthreads();
    }
    // attn.V: a = qd*256 + tid
    {
        int a = qd * 256 + tid;
        const u16* vr = Vt + ((size_t)b * AA + a) * TENC_;
        float s = 0.f;
        #pragma unroll 8
        for (int t8 = 0; t8 < 64; ++t8) {
            v8s vv = *(const v8s*)(vr + t8 * 8);
            #pragma unroll
            for (int e = 0; e < 8; ++e)
                s = fmaf(bf2f((u16)vv[e]), ps[t8 * 8 + e], s);
        }
        attnb[(size_t)b * AA + a] = f2bf(s);
    }
    __syncthreads();
}

__global__ __launch_bounds__(256) void recur_k(
    const u16* __restrict__ Eb, const u16* __restrict__ wpack0, const u16* __restrict__ wpack1,
    const float* __restrict__ bpk0, const float* __restrict__ bpk1,
    const u16* __restrict__ wqb, const u16* __restrict__ Kb, const u16* __restrict__ Vt,
    const float* __restrict__ bq,
    float* __restrict__ qbuf, float* __restrict__ sraw,
    u16* __restrict__ h0b, u16* __restrict__ h1b, u16* __restrict__ attnb,
    float* __restrict__ c0, float* __restrict__ c1, u16* __restrict__ h1a,
    int* flags, int* epoch, int* mbc)
{
    __shared__ __align__(16) char smem[65536];
    const int tid = threadIdx.x, bid = blockIdx.x;
    int n = 0;
    for (int t = 0; t < TDEC_; ++t) {
        const int cur = t & 1, prv = cur ^ 1;
        const u16* h0p = h0b + prv * (BQ * HH);
        u16*       h0c = h0b + cur * (BQ * HH);
        const u16* h1p = h1b + prv * (BQ * HH);
        u16*       h1c = h1b + cur * (BQ * HH);
        // phase A: layer-0 gates+cell. A = [e | attn | h0prev]
        lstm_phase(0, bid, tid, Eb + (size_t)t * BQ * AA, attnb, h0p, nullptr, nullptr,
                   wpack0, bpk0, c0, h0c, nullptr, smem);
        gbar(flags, epoch, bid, n);
        // phase B: layer-1 gates+cell. A = [h0cur | h1prev]
        lstm_phase(1, bid, tid, nullptr, nullptr, nullptr, h0c, h1p,
                   wpack1, bpk1, c1, h1c, h1a + (size_t)t * BQ * HH, smem);
        if (t == TDEC_ - 1) return;          // attn of last step unused
        gbar(flags, epoch, bid, n);
        // phase C: attention
        attn_phase(bid, tid, t, h1c, wqb, Kb, Vt, bq, qbuf, sraw, attnb, mbc, smem);
        gbar(flags, epoch, bid, n);
    }
}

// ---------------- LayerNorm+ReLU, bf16 in-place ----------------
__global__ __launch_bounds__(256) void ln_relu_b(u16* __restrict__ x, const float* __restrict__ g,
                                                 const float* __restrict__ bb) {
    int row = blockIdx.x, tid = threadIdx.x;
    u16* xr = x + (size_t)row * 2048;
    __shared__ float red[256];
    uint4 v = *(const uint4*)(xr + tid * 8);
    const u16* pv = (const u16*)&v;
    float lv[8];
    float s = 0.f;
    #pragma unroll
    for (int e = 0; e < 8; ++e) { lv[e] = bf2f(pv[e]); s += lv[e]; }
    red[tid] = s;
    __syncthreads();
    for (int off = 128; off; off >>= 1) {
        if (tid < off) red[tid] += red[tid + off];
        __syncthreads();
    }
    float mu = red[0] * (1.f / 2048.f);
    __syncthreads();
    s = 0.f;
    #pragma unroll
    for (int e = 0; e < 8; ++e) { float d = lv[e] - mu; s += d * d; }
    red[tid] = s;
    __syncthreads();
    for (int off = 128; off; off >>= 1) {
        if (tid < off) red[tid] += red[tid + off];
        __syncthreads();
    }
    float inv = rsqrtf(red[0] * (1.f / 2048.f) + 1e-5f);
    const float4 g1 = *(const float4*)(g + tid * 8), g2 = *(const float4*)(g + tid * 8 + 4);
    const float4 b1 = *(const float4*)(bb + tid * 8), b2 = *(const float4*)(bb + tid * 8 + 4);
    float gv[8] = {g1.x, g1.y, g1.z, g1.w, g2.x, g2.y, g2.z, g2.w};
    float bv[8] = {b1.x, b1.y, b1.z, b1.w, b2.x, b2.y, b2.z, b2.w};
    float o[8];
    #pragma unroll
    for (int e = 0; e < 8; ++e) o[e] = fmaxf((lv[e] - mu) * inv * gv[e] + bv[e], 0.f);
    *(uint4*)(xr + tid * 8) = pack8(make_float4(o[0], o[1], o[2], o[3]),
                                    make_float4(o[4], o[5], o[6], o[7]));
}

// ---------------- loss ----------------
__global__ void ce_loss(const float* __restrict__ logits, const int* __restrict__ target,
                        float* __restrict__ acc) {
    const int r = blockIdx.x;
    const float* row = logits + (size_t)r * VV;
    const int tid = threadIdx.x;
    __shared__ float red[256];
    float lv[4];
    float m = -1e30f;
    #pragma unroll
    for (int i = 0; i < 4; ++i) { lv[i] = row[tid + i * 256]; m = fmaxf(m, lv[i]); }
    red[tid] = m;
    __syncthreads();
    for (int off = 128; off; off >>= 1) {
        if (tid < off) red[tid] = fmaxf(red[tid], red[tid + off]);
        __syncthreads();
    }
    m = red[0];
    __syncthreads();
    float s = 0.f;
    #pragma unroll
    for (int i = 0; i < 4; ++i) s += expf(lv[i] - m);
    red[tid] = s;
    __syncthreads();
    for (int off = 128; off; off >>= 1) {
        if (tid < off) red[tid] += red[tid + off];
        __syncthreads();
    }
    if (tid == 0) {
        const float nll = logf(red[0]) + m - row[target[r]];
        atomicAdd(acc, nll);
    }
}

__global__ void finalize_loss(const float* __restrict__ acc, float* __restrict__ out) {
    out[0] = acc[0] * (1.f / 4096.f);
}

// ---------------- host ----------------
extern "C" void kernel_launch(void* const* d_in, const int* in_sizes, int n_in,
                              void* d_out, int out_size, void* d_ws, size_t ws_size,
                              hipStream_t stream) {
    const float* enc       = (const float*)d_in[0];
    const int*   target    = (const int*)d_in[1];
    const float* emb_table = (const float*)d_in[2];
    const float* att_wq    = (const float*)d_in[3];
    const float* att_bq    = (const float*)d_in[4];
    const float* att_wk    = (const float*)d_in[5];
    const float* att_bk    = (const float*)d_in[6];
    const float* att_wv    = (const float*)d_in[7];
    const float* att_bv    = (const float*)d_in[8];
    const float* w_ih0     = (const float*)d_in[9];
    const float* w_hh0     = (const float*)d_in[10];
    const float* b_ih0     = (const float*)d_in[11];
    const float* b_hh0     = (const float*)d_in[12];
    const float* w_ih1     = (const float*)d_in[13];
    const float* w_hh1     = (const float*)d_in[14];
    const float* b_ih1     = (const float*)d_in[15];
    const float* b_hh1     = (const float*)d_in[16];
    const float* mlp_w1    = (const float*)d_in[17];
    const float* mlp_b1    = (const float*)d_in[18];
    const float* ln_g      = (const float*)d_in[19];
    const float* ln_b      = (const float*)d_in[20];
    const float* mlp_w2    = (const float*)d_in[21];
    const float* mlp_b2    = (const float*)d_in[22];
    float* out = (float*)d_out;
    char* ws = (char*)d_ws;

    size_t off = 0;
    auto alloc = [&](size_t bytes) { size_t o = off; off += (bytes + 255) & ~(size_t)255; return o; };
    u16*   Kb     = (u16*)(ws + alloc((size_t)BQ * TENC_ * AA * 2));
    u16*   Vt     = (u16*)(ws + alloc((size_t)BQ * TENC_ * AA * 2));   // [b][a][t]
    u16*   Eb     = (u16*)(ws + alloc((size_t)TDEC_ * BQ * AA * 2));
    u16*   wpack0 = (u16*)(ws + alloc((size_t)4096 * 2048 * 2));
    u16*   wpack1 = (u16*)(ws + alloc((size_t)4096 * 2048 * 2));
    float* bpk0   = (float*)(ws + alloc(4096 * 4));
    float* bpk1   = (float*)(ws + alloc(4096 * 4));
    u16*   wkb    = (u16*)(ws + alloc((size_t)AA * HH * 2));
    u16*   wvb    = (u16*)(ws + alloc((size_t)AA * HH * 2));
    u16*   wqb    = (u16*)(ws + alloc((size_t)AA * HH * 2));
    u16*   w1b    = (u16*)(ws + alloc((size_t)2 * VV * HH * 2));
    u16*   w2b    = (u16*)(ws + alloc((size_t)VV * 2 * VV * 2));
    float* qbuf   = (float*)(ws + alloc((size_t)BQ * AA * 4));
    float* sraw   = (float*)(ws + alloc((size_t)BQ * TENC_ * 4));
    u16*   h0b    = (u16*)(ws + alloc((size_t)2 * BQ * HH * 2));   // double-buffered
    u16*   h1b    = (u16*)(ws + alloc((size_t)2 * BQ * HH * 2));
    u16*   attnb  = (u16*)(ws + alloc((size_t)BQ * AA * 2));
    float* c0     = (float*)(ws + alloc((size_t)BQ * HH * 4));
    float* c1     = (float*)(ws + alloc((size_t)BQ * HH * 4));
    u16*   h1a    = (u16*)(ws + alloc((size_t)TDEC_ * BQ * HH * 2));
    u16*   x1b    = (u16*)(ws + alloc((size_t)TDEC_ * BQ * 2 * VV * 2));
    float* lacc   = (float*)(ws + alloc(256));
    int*   barr   = (int*)(ws + alloc(16384));
    int* flags = barr;            // 128 ints
    int* epoch = barr + 256;      // own cacheline
    int* mbc   = barr + 512;      // 64 * 32 ints

    // ---- prologue ----
    build_wpack<<<4096, 256, 0, stream>>>(w_ih0, w_hh0, b_ih0, b_hh0, wpack0, bpk0);
    build_wpack<<<4096, 256, 0, stream>>>(w_ih1, w_hh1, b_ih1, b_hh1, wpack1, bpk1);
    conv_f2b<<<256, 256, 0, stream>>>(att_wk, wkb, AA * HH / 8);
    conv_f2b<<<256, 256, 0, stream>>>(att_wv, wvb, AA * HH / 8);
    conv_f2b<<<256, 256, 0, stream>>>(att_wq, wqb, AA * HH / 8);
    conv_f2b<<<1024, 256, 0, stream>>>(mlp_w1, w1b, 2 * VV * HH / 8);
    conv_f2b<<<1024, 256, 0, stream>>>(mlp_w2, w2b, VV * 2 * VV / 8);
    embed_k<<<TDEC_ * BQ, 64, 0, stream>>>(target, emb_table, Eb);

    hipMemsetAsync(h0b, 0, (size_t)2 * BQ * HH * 2, stream);
    hipMemsetAsync(h1b, 0, (size_t)2 * BQ * HH * 2, stream);
    hipMemsetAsync(attnb, 0, (size_t)BQ * AA * 2, stream);
    hipMemsetAsync(c0, 0, (size_t)BQ * HH * 4, stream);
    hipMemsetAsync(c1, 0, (size_t)BQ * HH * 4, stream);
    hipMemsetAsync(lacc, 0, 4, stream);
    hipMemsetAsync(barr, 0, 16384, stream);

    gemm_big<1, true><<<dim3(4, 256), 256, 0, stream>>>(enc, HH, wkb, HH, att_bk, Kb, AA, HH);
    gemm_big<3, true><<<dim3(4, 256), 256, 0, stream>>>(enc, HH, wvb, HH, att_bv, Vt, 0, HH);

    // ---- recurrence: one persistent kernel, 128 co-resident blocks ----
    recur_k<<<NBLK, 256, 0, stream>>>(Eb, wpack0, wpack1, bpk0, bpk1, wqb, Kb, Vt, att_bq,
                                      qbuf, sraw, h0b, h1b, attnb, c0, c1, h1a,
                                      flags, epoch, mbc);

    // ---- batched MLP head ----
    gemm_big<1, false><<<dim3(16, 32), 256, 0, stream>>>(h1a, HH, w1b, HH, mlp_b1, x1b, 2 * VV, HH);
    ln_relu_b<<<TDEC_ * BQ, 256, 0, stream>>>(x1b, ln_g, ln_b);
    gemm_big<2, false><<<dim3(8, 32), 256, 0, stream>>>(x1b, 2 * VV, w2b, 2 * VV, mlp_b2, out, VV, 2 * VV);

    ce_loss<<<BQ * TDEC_, 256, 0, stream>>>(out, target, lacc);
    finalize_loss<<<1, 1, 0, stream>>>(lacc, out + (size_t)BQ * TDEC_ * VV);
}

// Round 6
// 7980.226 us; speedup vs baseline: 3.3048x; 2.2833x over previous
//
#include <hip/hip_runtime.h>
#include <hip/hip_bf16.h>
#include <math.h>

#define BQ 64
#define TENC_ 512
#define TDEC_ 64
#define HH 1024
#define VV 1024
#define AA 512

typedef short v8s __attribute__((ext_vector_type(8)));
typedef float v4f __attribute__((ext_vector_type(4)));
typedef unsigned short u16;
typedef unsigned char u8;

__device__ __forceinline__ u16 f2bf(float f) {
    unsigned u = __builtin_bit_cast(unsigned, f);
    u = u + 0x7FFFu + ((u >> 16) & 1u);
    return (u16)(u >> 16);
}
__device__ __forceinline__ float bf2f(u16 h) {
    unsigned u = ((unsigned)h) << 16;
    return __builtin_bit_cast(float, u);
}
__device__ __forceinline__ uint4 pack8(const float4 a, const float4 b) {
    uint4 o;
    o.x = (unsigned)f2bf(a.x) | ((unsigned)f2bf(a.y) << 16);
    o.y = (unsigned)f2bf(a.z) | ((unsigned)f2bf(a.w) << 16);
    o.z = (unsigned)f2bf(b.x) | ((unsigned)f2bf(b.y) << 16);
    o.w = (unsigned)f2bf(b.z) | ((unsigned)f2bf(b.w) << 16);
    return o;
}

// fp8 e4m3fn, FTZ below 2^-6, clamp 448, RNE
__device__ __forceinline__ u8 ftof8(float f) {
    float af = fabsf(f);
    unsigned s = (__builtin_bit_cast(unsigned, f) >> 24) & 0x80;
    if (!(af >= 0.015625f)) return (u8)s;
    if (af > 448.f) af = 448.f;
    unsigned b = __builtin_bit_cast(unsigned, af);
    b += 0x7FFFFu + ((b >> 20) & 1u);
    return (u8)(s | (((b >> 23) - 120u) << 3) | ((b >> 20) & 7u));
}
__device__ __forceinline__ float f8tof(u8 v) {
    unsigned em = v & 0x7F;
    unsigned b = ((unsigned)(v & 0x80)) << 24;
    if (em) b |= (((em >> 3) + 120u) << 23) | ((em & 7u) << 20);
    return __builtin_bit_cast(float, b);
}

// ---------------- conversion / layout kernels ----------------

__global__ void conv_f2b(const float* __restrict__ src, u16* __restrict__ dst, int n8) {
    int i = blockIdx.x * 256 + threadIdx.x;
    if (i >= n8) return;
    const float4 a = *(const float4*)(src + (size_t)i * 8);
    const float4 b = *(const float4*)(src + (size_t)i * 8 + 4);
    ((uint4*)dst)[i] = pack8(a, b);
}

// wpack[(j*32 + r)][k], r = gate*8 + uu, orig row = gate*1024 + j*8 + uu; k<1024: wih, else whh.
__global__ void build_wpack(const float* __restrict__ wih, const float* __restrict__ whh,
                            const float* __restrict__ bih, const float* __restrict__ bhh,
                            u16* __restrict__ wpack, float* __restrict__ bpk) {
    int i = blockIdx.x * 256 + threadIdx.x;
    if (i >= 4096 * 2048 / 8) return;
    int rowp = i >> 8, k = (i & 255) * 8;
    int j = rowp >> 5, r = rowp & 31;
    int orig = ((r >> 3) << 10) + j * 8 + (r & 7);
    const float* s = (k < 1024) ? (wih + (size_t)orig * 1024 + k)
                                : (whh + (size_t)orig * 1024 + (k - 1024));
    ((uint4*)wpack)[i] = pack8(*(const float4*)s, *(const float4*)(s + 4));
    if (k == 0) bpk[rowp] = bih[orig] + bhh[orig];
}

__global__ void embed_k(const int* __restrict__ tgt, const float* __restrict__ table,
                        u16* __restrict__ Eb) {
    int bid = blockIdx.x;            // t*64 + b
    int t = bid >> 6, b = bid & 63;
    int tok = (t == 0) ? 0 : tgt[b * TDEC_ + t - 1];
    int lane = threadIdx.x;
    const float* src = table + (size_t)tok * AA + lane * 8;
    ((uint4*)Eb)[(size_t)bid * 64 + lane] = pack8(*(const float4*)src, *(const float4*)(src + 4));
}

// ---------------- big MFMA GEMM: 128x128 tile ----------------
// OUT: 1=bf16+bias, 2=f32+bias w/ (t*64+b)->(b*64+t) remap, 4=fp8+bias flat, 5=fp8+bias transposed Vt[b][n][t]
template<int OUT, bool AF32>
__global__ __launch_bounds__(256) void gemm_big(
    const void* __restrict__ Av, int lda,
    const u16* __restrict__ W, int ldw,
    const float* __restrict__ bias,
    void* __restrict__ outv, int ldo, int K) {
    __shared__ u16 As[128 * 128];
    __shared__ u16 Ws[128 * 128];
    const int tid = threadIdx.x;
    const int w = tid >> 6, lane = tid & 63;
    const int wm = w >> 1, wn = w & 1;
    const int li = lane & 15, lg = lane >> 4;
    const int mB = blockIdx.y * 128, nB = blockIdx.x * 128;
    v4f acc[4][4];
    #pragma unroll
    for (int mt = 0; mt < 4; ++mt)
        #pragma unroll
        for (int nt = 0; nt < 4; ++nt) acc[mt][nt] = (v4f){0.f, 0.f, 0.f, 0.f};
    for (int kc = 0; kc < K; kc += 128) {
        for (int it = 0; it < 8; ++it) {
            int flat = it * 256 + tid;
            int row = flat >> 4, c8 = flat & 15;
            uint4 val;
            if (AF32) {
                const float* Af = (const float*)Av + (size_t)(mB + row) * lda + kc + c8 * 8;
                val = pack8(*(const float4*)Af, *(const float4*)(Af + 4));
            } else {
                val = *(const uint4*)((const u16*)Av + (size_t)(mB + row) * lda + kc + c8 * 8);
            }
            int byte = (row * 256 + c8 * 16) ^ ((row & 7) << 4);
            *(uint4*)((char*)As + byte) = val;
            uint4 wv2 = *(const uint4*)(W + (size_t)(nB + row) * ldw + kc + c8 * 8);
            *(uint4*)((char*)Ws + byte) = wv2;
        }
        __syncthreads();
        for (int ks = 0; ks < 4; ++ks) {
            v8s wf[4];
            #pragma unroll
            for (int nt = 0; nt < 4; ++nt) {
                int row = wn * 64 + nt * 16 + li;
                int byte = (row * 256 + ks * 64 + lg * 16) ^ ((row & 7) << 4);
                wf[nt] = *(const v8s*)((char*)Ws + byte);
            }
            #pragma unroll
            for (int mt = 0; mt < 4; ++mt) {
                int row = wm * 64 + mt * 16 + li;
                int byte = (row * 256 + ks * 64 + lg * 16) ^ ((row & 7) << 4);
                v8s af = *(const v8s*)((char*)As + byte);
                #pragma unroll
                for (int nt = 0; nt < 4; ++nt)
                    acc[mt][nt] = __builtin_amdgcn_mfma_f32_16x16x32_bf16(af, wf[nt], acc[mt][nt], 0, 0, 0);
            }
        }
        __syncthreads();
    }
    #pragma unroll
    for (int mt = 0; mt < 4; ++mt) {
        #pragma unroll
        for (int r = 0; r < 4; ++r) {
            int m = mB + wm * 64 + mt * 16 + lg * 4 + r;
            #pragma unroll
            for (int nt = 0; nt < 4; ++nt) {
                int n = nB + wn * 64 + nt * 16 + li;
                float v = acc[mt][nt][r] + bias[n];
                if (OUT == 1) {
                    ((u16*)outv)[(size_t)m * ldo + n] = f2bf(v);
                } else if (OUT == 2) {
                    int mm = (m & 63) * TDEC_ + (m >> 6);
                    ((float*)outv)[(size_t)mm * ldo + n] = v;
                } else if (OUT == 4) {
                    ((u8*)outv)[(size_t)m * ldo + n] = ftof8(v);
                } else {
                    ((u8*)outv)[((size_t)(m >> 9) * AA + n) * TENC_ + (m & 511)] = ftof8(v);
                }
            }
        }
    }
}

// ---------------- fused LSTM gates+cell kernel (unit-sliced, full K) ----------------
// 128 blocks; block owns units [bid*8, bid*8+8) = packed rows [bid*32, bid*32+32).
// PHASE 0: A = [p0=Eb_t (ld 512) | p1=attnb (ld 512) | p2=h0prev (ld 1024)], K=2048
// PHASE 1: A = [p0=h0cur (ld 1024) | p1=h1prev (ld 1024)], K=2048
template<int PHASE>
__global__ __launch_bounds__(256) void lstm_f(
    const u16* __restrict__ p0, const u16* __restrict__ p1, const u16* __restrict__ p2,
    const u16* __restrict__ wpack, const float* __restrict__ bpk,
    float* __restrict__ cst, u16* __restrict__ hout, u16* __restrict__ h1a_t)
{
    __shared__ __align__(16) char smem[65536];
    const int tid = threadIdx.x, bid = blockIdx.x;
    const int lane = tid & 63, li = lane & 15, lg = lane >> 4, w = tid >> 6;

    auto srcp = [&](int c, int row, int k2) -> const u16* {
        int k = c * 256 + k2;
        if (PHASE == 0) {
            if (k < 512)  return p0 + row * 512 + k;
            if (k < 1024) return p1 + row * 512 + (k - 512);
            return p2 + row * 1024 + (k - 1024);
        } else {
            if (k < 1024) return p0 + row * 1024 + k;
            return p1 + row * 1024 + (k - 1024);
        }
    };
    uint4 rg[8];
    auto loadc = [&](int c) {
        #pragma unroll
        for (int it = 0; it < 8; ++it) {
            int flat = it * 256 + tid, row = flat >> 5, c16 = flat & 31;
            rg[it] = *(const uint4*)srcp(c, row, c16 * 8);
        }
    };
    auto writec = [&](int c) {
        char* buf = smem + (c & 1) * 32768;
        #pragma unroll
        for (int it = 0; it < 8; ++it) {
            int flat = it * 256 + tid, row = flat >> 5, c16 = flat & 31;
            int byte = (row * 512 + c16 * 16) ^ ((row & 7) << 4);
            *(uint4*)(buf + byte) = rg[it];
        }
    };

    loadc(0); writec(0); __syncthreads();
    v4f acc[2];
    acc[0] = (v4f){0.f, 0.f, 0.f, 0.f};
    acc[1] = (v4f){0.f, 0.f, 0.f, 0.f};
    const u16* wp0 = wpack + (size_t)(bid * 32 + li) * 2048;
    const u16* wp1 = wpack + (size_t)(bid * 32 + 16 + li) * 2048;
    for (int c = 0; c < 8; ++c) {
        if (c < 7) loadc(c + 1);
        char* buf = smem + (c & 1) * 32768;
        const int arow = w * 16 + li;
        #pragma unroll
        for (int ks = 0; ks < 8; ++ks) {
            v8s wf0 = *(const v8s*)(wp0 + c * 256 + ks * 32 + lg * 8);
            v8s wf1 = *(const v8s*)(wp1 + c * 256 + ks * 32 + lg * 8);
            int byte = (arow * 512 + ks * 64 + lg * 16) ^ ((arow & 7) << 4);
            v8s af = *(const v8s*)(buf + byte);
            acc[0] = __builtin_amdgcn_mfma_f32_16x16x32_bf16(af, wf0, acc[0], 0, 0, 0);
            acc[1] = __builtin_amdgcn_mfma_f32_16x16x32_bf16(af, wf1, acc[1], 0, 0, 0);
        }
        if (c < 7) writec(c + 1);
        __syncthreads();
    }
    float* gl = (float*)smem;
    #pragma unroll
    for (int nt = 0; nt < 2; ++nt)
        #pragma unroll
        for (int r = 0; r < 4; ++r)
            gl[(w * 16 + lg * 4 + r) * 33 + nt * 16 + li] = acc[nt][r];
    __syncthreads();
    #pragma unroll
    for (int h = 0; h < 2; ++h) {
        int item = h * 256 + tid, m = item & 63, uu = item >> 6;
        float gi = gl[m * 33 + uu]      + bpk[bid * 32 + uu];
        float gf = gl[m * 33 + 8 + uu]  + bpk[bid * 32 + 8 + uu];
        float gg = gl[m * 33 + 16 + uu] + bpk[bid * 32 + 16 + uu];
        float go = gl[m * 33 + 24 + uu] + bpk[bid * 32 + 24 + uu];
        int ci = m * 1024 + bid * 8 + uu;
        float ii = 1.f / (1.f + expf(-gi));
        float ff = 1.f / (1.f + expf(-gf));
        float oo = 1.f / (1.f + expf(-go));
        float c2 = ff * cst[ci] + ii * tanhf(gg);
        float hv = oo * tanhf(c2);
        cst[ci] = c2;
        hout[ci] = f2bf(hv);
        if (PHASE == 1) h1a_t[ci] = f2bf(hv);
    }
}

// ---------------- q projection: q[64,512] = h1 @ wq^T + bq ----------------
__global__ __launch_bounds__(256) void q_k(const u16* __restrict__ h1, const u16* __restrict__ wq,
                                           const float* __restrict__ bq, float* __restrict__ qf) {
    const int tid = threadIdx.x, w = tid >> 6, lane = tid & 63;
    const int li = lane & 15, lg = lane >> 4;
    const int n = blockIdx.x * 64 + w * 16 + li;
    const u16* wr = wq + (size_t)n * 1024 + lg * 8;
    v4f acc[4];
    #pragma unroll
    for (int mt = 0; mt < 4; ++mt) acc[mt] = (v4f){0.f, 0.f, 0.f, 0.f};
    for (int ks = 0; ks < 32; ++ks) {
        v8s wf = *(const v8s*)(wr + ks * 32);
        #pragma unroll
        for (int mt = 0; mt < 4; ++mt) {
            v8s af = *(const v8s*)(h1 + (size_t)(mt * 16 + li) * 1024 + ks * 32 + lg * 8);
            acc[mt] = __builtin_amdgcn_mfma_f32_16x16x32_bf16(af, wf, acc[mt], 0, 0, 0);
        }
    }
    const float bv = bq[n];
    #pragma unroll
    for (int mt = 0; mt < 4; ++mt)
        #pragma unroll
        for (int r = 0; r < 4; ++r)
            qf[(size_t)(mt * 16 + lg * 4 + r) * AA + n] = acc[mt][r] + bv;
}

// ---------------- scores: sraw[b][tt] = dot(K8[b,tt,:], q[b,:]) ----------------
__global__ __launch_bounds__(256) void sc_k(const u8* __restrict__ K8, const float* __restrict__ qf,
                                            float* __restrict__ sraw) {
    __shared__ float qs[AA];
    const int b = blockIdx.x, s = blockIdx.y, tid = threadIdx.x;
    qs[tid] = qf[(size_t)b * AA + tid];
    qs[tid + 256] = qf[(size_t)b * AA + 256 + tid];
    __syncthreads();
    const int w = tid >> 6, lane = tid & 63;
    float qv[8];
    #pragma unroll
    for (int e = 0; e < 8; ++e) qv[e] = qs[lane * 8 + e];
    for (int r = 0; r < 32; ++r) {
        int tt = s * 128 + w * 32 + r;
        uint2 kv = *(const uint2*)(K8 + ((size_t)b * TENC_ + tt) * AA + lane * 8);
        const u8* kp = (const u8*)&kv;
        float sum = 0.f;
        #pragma unroll
        for (int e = 0; e < 8; ++e) sum = fmaf(f8tof(kp[e]), qv[e], sum);
        sum += __shfl_xor(sum, 1);  sum += __shfl_xor(sum, 2);
        sum += __shfl_xor(sum, 4);  sum += __shfl_xor(sum, 8);
        sum += __shfl_xor(sum, 16); sum += __shfl_xor(sum, 32);
        if (lane == 0) sraw[(size_t)b * TENC_ + tt] = sum;
    }
}

// ---------------- softmax + attn.V : grid (64, 2), half the a-range per block ----------------
__global__ __launch_bounds__(256) void av_k(const float* __restrict__ sraw, const u8* __restrict__ Vt8,
                                            u16* __restrict__ attnb) {
    __shared__ float red[256];
    __shared__ float ps[TENC_];
    const int b = blockIdx.x, hf = blockIdx.y, tid = threadIdx.x;
    float v0 = sraw[(size_t)b * TENC_ + tid], v1 = sraw[(size_t)b * TENC_ + 256 + tid];
    red[tid] = fmaxf(v0, v1);
    __syncthreads();
    for (int off = 128; off; off >>= 1) {
        if (tid < off) red[tid] = fmaxf(red[tid], red[tid + off]);
        __syncthreads();
    }
    float m = red[0];
    __syncthreads();
    float e0 = expf(v0 - m), e1 = expf(v1 - m);
    red[tid] = e0 + e1;
    __syncthreads();
    for (int off = 128; off; off >>= 1) {
        if (tid < off) red[tid] += red[tid + off];
        __syncthreads();
    }
    float inv = 1.f / red[0];
    ps[tid] = e0 * inv; ps[tid + 256] = e1 * inv;
    __syncthreads();
    const int a = hf * 256 + tid;
    const u8* vr = Vt8 + ((size_t)b * AA + a) * TENC_;
    float sum = 0.f;
    #pragma unroll 4
    for (int t8 = 0; t8 < 64; ++t8) {
        uint2 vv = *(const uint2*)(vr + t8 * 8);
        const u8* vp = (const u8*)&vv;
        #pragma unroll
        for (int e = 0; e < 8; ++e) sum = fmaf(f8tof(vp[e]), ps[t8 * 8 + e], sum);
    }
    attnb[(size_t)b * AA + a] = f2bf(sum);
}

// ---------------- LayerNorm+ReLU, bf16 in-place ----------------
__global__ __launch_bounds__(256) void ln_relu_b(u16* __restrict__ x, const float* __restrict__ g,
                                                 const float* __restrict__ bb) {
    int row = blockIdx.x, tid = threadIdx.x;
    u16* xr = x + (size_t)row * 2048;
    __shared__ float red[256];
    uint4 v = *(const uint4*)(xr + tid * 8);
    const u16* pv = (const u16*)&v;
    float lv[8];
    float s = 0.f;
    #pragma unroll
    for (int e = 0; e < 8; ++e) { lv[e] = bf2f(pv[e]); s += lv[e]; }
    red[tid] = s;
    __syncthreads();
    for (int off = 128; off; off >>= 1) {
        if (tid < off) red[tid] += red[tid + off];
        __syncthreads();
    }
    float mu = red[0] * (1.f / 2048.f);
    __syncthreads();
    s = 0.f;
    #pragma unroll
    for (int e = 0; e < 8; ++e) { float d = lv[e] - mu; s += d * d; }
    red[tid] = s;
    __syncthreads();
    for (int off = 128; off; off >>= 1) {
        if (tid < off) red[tid] += red[tid + off];
        __syncthreads();
    }
    float inv = rsqrtf(red[0] * (1.f / 2048.f) + 1e-5f);
    const float4 g1 = *(const float4*)(g + tid * 8), g2 = *(const float4*)(g + tid * 8 + 4);
    const float4 b1 = *(const float4*)(bb + tid * 8), b2 = *(const float4*)(bb + tid * 8 + 4);
    float gv[8] = {g1.x, g1.y, g1.z, g1.w, g2.x, g2.y, g2.z, g2.w};
    float bv[8] = {b1.x, b1.y, b1.z, b1.w, b2.x, b2.y, b2.z, b2.w};
    float o[8];
    #pragma unroll
    for (int e = 0; e < 8; ++e) o[e] = fmaxf((lv[e] - mu) * inv * gv[e] + bv[e], 0.f);
    *(uint4*)(xr + tid * 8) = pack8(make_float4(o[0], o[1], o[2], o[3]),
                                    make_float4(o[4], o[5], o[6], o[7]));
}

// ---------------- loss ----------------
__global__ void ce_loss(const float* __restrict__ logits, const int* __restrict__ target,
                        float* __restrict__ acc) {
    const int r = blockIdx.x;
    const float* row = logits + (size_t)r * VV;
    const int tid = threadIdx.x;
    __shared__ float red[256];
    float lv[4];
    float m = -1e30f;
    #pragma unroll
    for (int i = 0; i < 4; ++i) { lv[i] = row[tid + i * 256]; m = fmaxf(m, lv[i]); }
    red[tid] = m;
    __syncthreads();
    for (int off = 128; off; off >>= 1) {
        if (tid < off) red[tid] = fmaxf(red[tid], red[tid + off]);
        __syncthreads();
    }
    m = red[0];
    __syncthreads();
    float s = 0.f;
    #pragma unroll
    for (int i = 0; i < 4; ++i) s += expf(lv[i] - m);
    red[tid] = s;
    __syncthreads();
    for (int off = 128; off; off >>= 1) {
        if (tid < off) red[tid] += red[tid + off];
        __syncthreads();
    }
    if (tid == 0) {
        const float nll = logf(red[0]) + m - row[target[r]];
        atomicAdd(acc, nll);
    }
}

__global__ void finalize_loss(const float* __restrict__ acc, float* __restrict__ out) {
    out[0] = acc[0] * (1.f / 4096.f);
}

// ---------------- host ----------------
extern "C" void kernel_launch(void* const* d_in, const int* in_sizes, int n_in,
                              void* d_out, int out_size, void* d_ws, size_t ws_size,
                              hipStream_t stream) {
    const float* enc       = (const float*)d_in[0];
    const int*   target    = (const int*)d_in[1];
    const float* emb_table = (const float*)d_in[2];
    const float* att_wq    = (const float*)d_in[3];
    const float* att_bq    = (const float*)d_in[4];
    const float* att_wk    = (const float*)d_in[5];
    const float* att_bk    = (const float*)d_in[6];
    const float* att_wv    = (const float*)d_in[7];
    const float* att_bv    = (const float*)d_in[8];
    const float* w_ih0     = (const float*)d_in[9];
    const float* w_hh0     = (const float*)d_in[10];
    const float* b_ih0     = (const float*)d_in[11];
    const float* b_hh0     = (const float*)d_in[12];
    const float* w_ih1     = (const float*)d_in[13];
    const float* w_hh1     = (const float*)d_in[14];
    const float* b_ih1     = (const float*)d_in[15];
    const float* b_hh1     = (const float*)d_in[16];
    const float* mlp_w1    = (const float*)d_in[17];
    const float* mlp_b1    = (const float*)d_in[18];
    const float* ln_g      = (const float*)d_in[19];
    const float* ln_b      = (const float*)d_in[20];
    const float* mlp_w2    = (const float*)d_in[21];
    const float* mlp_b2    = (const float*)d_in[22];
    float* out = (float*)d_out;
    char* ws = (char*)d_ws;

    size_t off = 0;
    auto alloc = [&](size_t bytes) { size_t o = off; off += (bytes + 255) & ~(size_t)255; return o; };
    u8*    Kf8    = (u8*)(ws + alloc((size_t)BQ * TENC_ * AA));
    u8*    Vt8    = (u8*)(ws + alloc((size_t)BQ * TENC_ * AA));      // [b][a][t]
    u16*   Eb     = (u16*)(ws + alloc((size_t)TDEC_ * BQ * AA * 2));
    u16*   wpack0 = (u16*)(ws + alloc((size_t)4096 * 2048 * 2));
    u16*   wpack1 = (u16*)(ws + alloc((size_t)4096 * 2048 * 2));
    float* bpk0   = (float*)(ws + alloc(4096 * 4));
    float* bpk1   = (float*)(ws + alloc(4096 * 4));
    u16*   wkb    = (u16*)(ws + alloc((size_t)AA * HH * 2));
    u16*   wvb    = (u16*)(ws + alloc((size_t)AA * HH * 2));
    u16*   wqb    = (u16*)(ws + alloc((size_t)AA * HH * 2));
    u16*   w1b    = (u16*)(ws + alloc((size_t)2 * VV * HH * 2));
    u16*   w2b    = (u16*)(ws + alloc((size_t)VV * 2 * VV * 2));
    float* qf     = (float*)(ws + alloc((size_t)BQ * AA * 4));
    float* sraw   = (float*)(ws + alloc((size_t)BQ * TENC_ * 4));
    u16*   h0b    = (u16*)(ws + alloc((size_t)2 * BQ * HH * 2));     // parity double-buffered
    u16*   h1b    = (u16*)(ws + alloc((size_t)2 * BQ * HH * 2));
    u16*   attnb  = (u16*)(ws + alloc((size_t)BQ * AA * 2));
    float* c0     = (float*)(ws + alloc((size_t)BQ * HH * 4));
    float* c1     = (float*)(ws + alloc((size_t)BQ * HH * 4));
    u16*   h1a    = (u16*)(ws + alloc((size_t)TDEC_ * BQ * HH * 2));
    u16*   x1b    = (u16*)(ws + alloc((size_t)TDEC_ * BQ * 2 * VV * 2));
    float* lacc   = (float*)(ws + alloc(256));

    // ---- prologue ----
    build_wpack<<<4096, 256, 0, stream>>>(w_ih0, w_hh0, b_ih0, b_hh0, wpack0, bpk0);
    build_wpack<<<4096, 256, 0, stream>>>(w_ih1, w_hh1, b_ih1, b_hh1, wpack1, bpk1);
    conv_f2b<<<256, 256, 0, stream>>>(att_wk, wkb, AA * HH / 8);
    conv_f2b<<<256, 256, 0, stream>>>(att_wv, wvb, AA * HH / 8);
    conv_f2b<<<256, 256, 0, stream>>>(att_wq, wqb, AA * HH / 8);
    conv_f2b<<<1024, 256, 0, stream>>>(mlp_w1, w1b, 2 * VV * HH / 8);
    conv_f2b<<<1024, 256, 0, stream>>>(mlp_w2, w2b, VV * 2 * VV / 8);
    embed_k<<<TDEC_ * BQ, 64, 0, stream>>>(target, emb_table, Eb);

    hipMemsetAsync(h0b, 0, (size_t)2 * BQ * HH * 2, stream);
    hipMemsetAsync(h1b, 0, (size_t)2 * BQ * HH * 2, stream);
    hipMemsetAsync(attnb, 0, (size_t)BQ * AA * 2, stream);
    hipMemsetAsync(c0, 0, (size_t)BQ * HH * 4, stream);
    hipMemsetAsync(c1, 0, (size_t)BQ * HH * 4, stream);
    hipMemsetAsync(lacc, 0, 4, stream);

    // K/V projections -> fp8 (K flat [b*T][a], V transposed [b][a][t])
    gemm_big<4, true><<<dim3(4, 256), 256, 0, stream>>>(enc, HH, wkb, HH, att_bk, Kf8, AA, HH);
    gemm_big<5, true><<<dim3(4, 256), 256, 0, stream>>>(enc, HH, wvb, HH, att_bv, Vt8, 0, HH);

    // ---- recurrence: 5 launches/step ----
    for (int t = 0; t < TDEC_; ++t) {
        const int cur = t & 1, prv = cur ^ 1;
        u16* h0c = h0b + cur * (BQ * HH);
        u16* h1c = h1b + cur * (BQ * HH);
        lstm_f<0><<<128, 256, 0, stream>>>(Eb + (size_t)t * BQ * AA, attnb, h0b + prv * (BQ * HH),
                                           wpack0, bpk0, c0, h0c, nullptr);
        lstm_f<1><<<128, 256, 0, stream>>>(h0c, h1b + prv * (BQ * HH), nullptr,
                                           wpack1, bpk1, c1, h1c, h1a + (size_t)t * BQ * HH);
        if (t < TDEC_ - 1) {
            q_k<<<8, 256, 0, stream>>>(h1c, wqb, att_bq, qf);
            sc_k<<<dim3(64, 4), 256, 0, stream>>>(Kf8, qf, sraw);
            av_k<<<dim3(64, 2), 256, 0, stream>>>(sraw, Vt8, attnb);
        }
    }

    // ---- batched MLP head ----
    gemm_big<1, false><<<dim3(16, 32), 256, 0, stream>>>(h1a, HH, w1b, HH, mlp_b1, x1b, 2 * VV, HH);
    ln_relu_b<<<TDEC_ * BQ, 256, 0, stream>>>(x1b, ln_g, ln_b);
    gemm_big<2, false><<<dim3(8, 32), 256, 0, stream>>>(x1b, 2 * VV, w2b, 2 * VV, mlp_b2, out, VV, 2 * VV);

    ce_loss<<<BQ * TDEC_, 256, 0, stream>>>(out, target, lacc);
    finalize_loss<<<1, 1, 0, stream>>>(lacc, out + (size_t)BQ * TDEC_ * VV);
}